// Round 27
// baseline (33.173 us; speedup 1.0000x reference)
//
#include <hip/hip_runtime.h>
#include <stdint.h>

// Fused 3x3 neighborhood-attention, 2-row SHARED-LOAD blocks.
//  Block = rows {y0,y0+1}; 256 threads = 4 waves (16-ch quarters), lane=quad.
//  Pass A per channel: 4 nbr rows {ym,y0,y0+1,yp2} + 2 ref rows = 6 loads
//    feed BOTH output rows (3 VMEM/output-row vs 4 in R19: -25% VMEM instrs,
//    the lever of the VMEM-service-rate model; R23 only shared cache lines).
//    Row-sumsq s2row[4][6] shared between outputs; dtA/dtB separate.
//  Reduce: 4 rounds through one [10][4][256] 40KB buffer; 2 softmaxes/thread;
//  both rows' coefs in LDS (18KB). Pass B: 6 loads/ch -> both outputs.
// Shapes: [b=2, c=64, h=256, w=256] fp32.

constexpr int C = 64, H = 256, W = 256, HW = H * W;
constexpr int B = 2;

__global__ __launch_bounds__(256, 1) void fused2r_kernel(const float* __restrict__ nbr,
                                                         const float* __restrict__ ref,
                                                         float* __restrict__ out) {
  __shared__ float buf[10][4][W];     // 40,960 B; multipurpose (coefs: 18KB)

  const int tid  = threadIdx.x;
  const int lane = tid & 63;          // quad index; x0 = 4*lane
  const int wv   = tid >> 6;          // channel quarter 0..3
  const int x0   = lane * 4;

  // XCD band swizzle: 256 blocks, bijective
  const int rp = ((blockIdx.x & 7) << 5) | (blockIdx.x >> 3);
  const int b  = rp >> 7;
  const int y0 = (rp & 127) * 2;      // even; rows {y0, y0+1}
  const int ym  = (y0 == 0)     ? 1     : y0 - 1;   // jnp reflect (row -1 -> 1)
  const int yp2 = (y0 == H - 2) ? H - 2 : y0 + 2;   // reflect (row 256 -> 254)

  const float* nbase = nbr + (size_t)b * C * HW;
  const float* rrowA = ref + (size_t)b * C * HW + y0 * W;        // + c*HW + x
  const float* rrowB = rrowA + W;
  float*       obaseA = out + (size_t)b * C * HW + y0 * W;
  float*       obaseB = obaseA + W;
  const int off4[4] = {ym * W, y0 * W, (y0 + 1) * W, yp2 * W};
  const int c0 = wv * 16;

  // ================= Pass A: accumulate both rows =================
  float dtA[4][9], dtB[4][9], s2r[4][6], srA[4], srB[4];
#pragma unroll
  for (int e = 0; e < 4; ++e) {
    srA[e] = 0.f; srB[e] = 0.f;
#pragma unroll
    for (int k = 0; k < 9; ++k) { dtA[e][k] = 0.f; dtB[e][k] = 0.f; }
  }
#pragma unroll
  for (int rr = 0; rr < 4; ++rr)
#pragma unroll
    for (int i = 0; i < 6; ++i) s2r[rr][i] = 0.f;

#pragma unroll 2
  for (int cc = 0; cc < 16; ++cc) {
    const float* cb = nbase + (size_t)(c0 + cc) * HW;
    const float4 r0 = *(const float4*)(cb + off4[0] + x0);
    const float4 r1 = *(const float4*)(cb + off4[1] + x0);
    const float4 r2 = *(const float4*)(cb + off4[2] + x0);
    const float4 r3 = *(const float4*)(cb + off4[3] + x0);
    const float4 fA = *(const float4*)(rrowA + (size_t)(c0 + cc) * HW + x0);
    const float4 fB = *(const float4*)(rrowB + (size_t)(c0 + cc) * HW + x0);
    const float feA[4] = {fA.x, fA.y, fA.z, fA.w};
    const float feB[4] = {fB.x, fB.y, fB.z, fB.w};
#pragma unroll
    for (int e = 0; e < 4; ++e) {
      srA[e] = fmaf(feA[e], feA[e], srA[e]);
      srB[e] = fmaf(feB[e], feB[e], srB[e]);
    }
    const float4 rows[4] = {r0, r1, r2, r3};
#pragma unroll
    for (int rr = 0; rr < 4; ++rr) {
      const float4 v = rows[rr];
      float L = __shfl(v.w, lane - 1);
      float R = __shfl(v.x, lane + 1);
      if (lane == 0)  L = v.y;        // reflect: x=-1 -> 1
      if (lane == 63) R = v.z;        // reflect: x=256 -> 254
      const float win[6] = {L, v.x, v.y, v.z, v.w, R};
#pragma unroll
      for (int i = 0; i < 6; ++i) s2r[rr][i] = fmaf(win[i], win[i], s2r[rr][i]);
      if (rr < 3) {                   // output row A uses data rows 0,1,2
        const int kb = rr * 3;
#pragma unroll
        for (int e = 0; e < 4; ++e)
#pragma unroll
          for (int cx = 0; cx < 3; ++cx)
            dtA[e][kb + cx] = fmaf(feA[e], win[e + cx], dtA[e][kb + cx]);
      }
      if (rr > 0) {                   // output row B uses data rows 1,2,3
        const int kb = (rr - 1) * 3;
#pragma unroll
        for (int e = 0; e < 4; ++e)
#pragma unroll
          for (int cx = 0; cx < 3; ++cx)
            dtB[e][kb + cx] = fmaf(feB[e], win[e + cx], dtB[e][kb + cx]);
      }
    }
  }

  // ---- reduce row A, round 1: dtA + srA ----
#pragma unroll
  for (int k = 0; k < 9; ++k)
    *(float4*)&buf[k][wv][x0] = float4{dtA[0][k], dtA[1][k], dtA[2][k], dtA[3][k]};
  *(float4*)&buf[9][wv][x0] = float4{srA[0], srA[1], srA[2], srA[3]};
  __syncthreads();
  float tdA[9];
#pragma unroll
  for (int k = 0; k < 9; ++k)
    tdA[k] = buf[k][0][tid] + buf[k][1][tid] + buf[k][2][tid] + buf[k][3][tid];
  const float tsrA = buf[9][0][tid] + buf[9][1][tid] + buf[9][2][tid] + buf[9][3][tid];
  __syncthreads();

  // ---- reduce row A, round 2: sqA (= s2r[k/3][e+k%3]) ----
#pragma unroll
  for (int k = 0; k < 9; ++k) {
    const int r = k / 3, cx = k % 3;
    *(float4*)&buf[k][wv][x0] = float4{s2r[r][cx], s2r[r][cx + 1], s2r[r][cx + 2], s2r[r][cx + 3]};
  }
  __syncthreads();
  float cfvA[9];
  {
    float tq[9];
#pragma unroll
    for (int k = 0; k < 9; ++k)
      tq[k] = buf[k][0][tid] + buf[k][1][tid] + buf[k][2][tid] + buf[k][3][tid];
    const float invr = __frsqrt_rn(fmaxf(tsrA, 1e-24f));
    float d[9], invp[9];
    float mx = -INFINITY;
#pragma unroll
    for (int k = 0; k < 9; ++k) {
      invp[k] = __frsqrt_rn(fmaxf(tq[k], 1e-24f));
      d[k]    = tdA[k] * invr * invp[k];
      mx      = fmaxf(mx, d[k]);
    }
    float s = 0.f;
#pragma unroll
    for (int k = 0; k < 9; ++k) { cfvA[k] = __expf(d[k] - mx); s += cfvA[k]; }
    const float sinv = 1.0f / s;
#pragma unroll
    for (int k = 0; k < 9; ++k) cfvA[k] *= sinv * invp[k];   // patch l2norm folded
  }
  __syncthreads();

  // ---- reduce row B, round 1: dtB + srB ----
#pragma unroll
  for (int k = 0; k < 9; ++k)
    *(float4*)&buf[k][wv][x0] = float4{dtB[0][k], dtB[1][k], dtB[2][k], dtB[3][k]};
  *(float4*)&buf[9][wv][x0] = float4{srB[0], srB[1], srB[2], srB[3]};
  __syncthreads();
  float tdB[9];
#pragma unroll
  for (int k = 0; k < 9; ++k)
    tdB[k] = buf[k][0][tid] + buf[k][1][tid] + buf[k][2][tid] + buf[k][3][tid];
  const float tsrB = buf[9][0][tid] + buf[9][1][tid] + buf[9][2][tid] + buf[9][3][tid];
  __syncthreads();

  // ---- reduce row B, round 2: sqB (= s2r[k/3+1][e+k%3]) ----
#pragma unroll
  for (int k = 0; k < 9; ++k) {
    const int r = k / 3 + 1, cx = k % 3;
    *(float4*)&buf[k][wv][x0] = float4{s2r[r][cx], s2r[r][cx + 1], s2r[r][cx + 2], s2r[r][cx + 3]};
  }
  __syncthreads();
  float cfvB[9];
  {
    float tq[9];
#pragma unroll
    for (int k = 0; k < 9; ++k)
      tq[k] = buf[k][0][tid] + buf[k][1][tid] + buf[k][2][tid] + buf[k][3][tid];
    const float invr = __frsqrt_rn(fmaxf(tsrB, 1e-24f));
    float d[9], invp[9];
    float mx = -INFINITY;
#pragma unroll
    for (int k = 0; k < 9; ++k) {
      invp[k] = __frsqrt_rn(fmaxf(tq[k], 1e-24f));
      d[k]    = tdB[k] * invr * invp[k];
      mx      = fmaxf(mx, d[k]);
    }
    float s = 0.f;
#pragma unroll
    for (int k = 0; k < 9; ++k) { cfvB[k] = __expf(d[k] - mx); s += cfvB[k]; }
    const float sinv = 1.0f / s;
#pragma unroll
    for (int k = 0; k < 9; ++k) cfvB[k] *= sinv * invp[k];
  }
  __syncthreads();   // all reads done; overwrite with coefs

  float* wc = &buf[0][0][0];           // coefs: A at [k*256+px], B at [(9+k)*256+px]
#pragma unroll
  for (int k = 0; k < 9; ++k) {
    wc[k * W + tid]       = cfvA[k];
    wc[(9 + k) * W + tid] = cfvB[k];
  }
  __syncthreads();

  // ================= Pass B: apply both rows (L2/L3-hot re-read) =================
  float4 cfA[9], cfB[9];
#pragma unroll
  for (int k = 0; k < 9; ++k) {
    cfA[k] = *(const float4*)&wc[k * W + x0];
    cfB[k] = *(const float4*)&wc[(9 + k) * W + x0];
  }

#pragma unroll 2
  for (int cc = 0; cc < 16; ++cc) {
    const int c = c0 + cc;
    const float* cb = nbase + (size_t)c * HW;
    const float4 r0 = *(const float4*)(cb + off4[0] + x0);
    const float4 r1 = *(const float4*)(cb + off4[1] + x0);
    const float4 r2 = *(const float4*)(cb + off4[2] + x0);
    const float4 r3 = *(const float4*)(cb + off4[3] + x0);
    const float4 fA = *(const float4*)(rrowA + (size_t)c * HW + x0);
    const float4 fB = *(const float4*)(rrowB + (size_t)c * HW + x0);

    float aggA[4] = {0.f, 0.f, 0.f, 0.f};
    float aggB[4] = {0.f, 0.f, 0.f, 0.f};
    const float4 rows[4] = {r0, r1, r2, r3};
#pragma unroll
    for (int rr = 0; rr < 4; ++rr) {
      const float4 v = rows[rr];
      float L = __shfl(v.w, lane - 1);
      float R = __shfl(v.x, lane + 1);
      if (lane == 0)  L = v.y;
      if (lane == 63) R = v.z;
      const float win[6] = {L, v.x, v.y, v.z, v.w, R};
      if (rr < 3) {
#pragma unroll
        for (int cx = 0; cx < 3; ++cx) {
          const float4 cf = cfA[rr * 3 + cx];
          const float cfe[4] = {cf.x, cf.y, cf.z, cf.w};
#pragma unroll
          for (int e = 0; e < 4; ++e) aggA[e] = fmaf(cfe[e], win[e + cx], aggA[e]);
        }
      }
      if (rr > 0) {
#pragma unroll
        for (int cx = 0; cx < 3; ++cx) {
          const float4 cf = cfB[(rr - 1) * 3 + cx];
          const float cfe[4] = {cf.x, cf.y, cf.z, cf.w};
#pragma unroll
          for (int e = 0; e < 4; ++e) aggB[e] = fmaf(cfe[e], win[e + cx], aggB[e]);
        }
      }
    }
    const float ctrA[4] = {r1.x, r1.y, r1.z, r1.w};   // center of row y0
    const float ctrB[4] = {r2.x, r2.y, r2.z, r2.w};   // center of row y0+1
    const float feA[4]  = {fA.x, fA.y, fA.z, fA.w};
    const float feB[4]  = {fB.x, fB.y, fB.z, fB.w};
    float oA[4], oB[4];
#pragma unroll
    for (int e = 0; e < 4; ++e) {
      const float dA = ctrA[e] - feA[e];
      const float dB = ctrB[e] - feB[e];
      oA[e] = aggA[e] * __expf(-(dA * dA));   // exp(ALPHA*(nbr-ref)^2), ALPHA=-1
      oB[e] = aggB[e] * __expf(-(dB * dB));
    }
    float4 o4A, o4B;
    o4A.x = oA[0]; o4A.y = oA[1]; o4A.z = oA[2]; o4A.w = oA[3];
    o4B.x = oB[0]; o4B.y = oB[1]; o4B.z = oB[2]; o4B.w = oB[3];
    *(float4*)(obaseA + (size_t)c * HW + x0) = o4A;
    *(float4*)(obaseB + (size_t)c * HW + x0) = o4B;
  }
}

extern "C" void kernel_launch(void* const* d_in, const int* in_sizes, int n_in,
                              void* d_out, int out_size, void* d_ws, size_t ws_size,
                              hipStream_t stream) {
  const float* nbr = (const float*)d_in[0];
  const float* ref = (const float*)d_in[1];
  float*       out = (float*)d_out;
  fused2r_kernel<<<dim3(B * H / 2), dim3(256), 0, stream>>>(nbr, ref, out);   // 256 two-row blocks
}